// Round 6
// baseline (3379.691 us; speedup 1.0000x reference)
//
#include <hip/hip_runtime.h>
#include <math.h>

#define TS 512
#define NB 64
#define NF 64
#define NE 256
#define NH 512
#define NO 128

#define NGRP 4     // batch groups (16 rows each)
#define NSLC 64    // h-slices per group (8 h-idx each)
#define RPG  16    // rows per group
#define SA   584   // LDS A row stride (bf16 elems): 576 + 8 pad

// ws layout (float words)
#define OFF_WCOMB 0        // 2048*64
#define OFF_BCOMB 131072   // 2048
#define OFF_BUFHI 133120   // 2*64*256 u32 (packed hi-bf16 pairs)
#define OFF_BUFLO 165888   // 2*64*256 u32 (packed lo-bf16 pairs)
#define OFF_POOL  198656   // 64*512
#define OFF_FLAGS 231424   // 4*512*64*2 ints (t-indexed, no init needed)

#define FLAGVAL 0x0000000100000001ULL

typedef short bf16x8 __attribute__((ext_vector_type(8)));
typedef short bf16x4 __attribute__((ext_vector_type(4)));
typedef float f32x4 __attribute__((ext_vector_type(4)));
typedef unsigned long long u64;

union F8 { bf16x8 s; unsigned short u[8]; };
union F4 { bf16x4 s; unsigned short u[4]; };

__device__ __forceinline__ unsigned short f2bf(float f) {
    unsigned u = __float_as_uint(f);
    u += 0x7fffu + ((u >> 16) & 1u);
    return (unsigned short)(u >> 16);
}
__device__ __forceinline__ float bf2f(unsigned short h) {
    return __uint_as_float(((unsigned)h) << 16);
}
__device__ __forceinline__ float fast_sigmoid(float v) {
    return 1.f / (1.f + __expf(-v));
}
__device__ __forceinline__ float fast_tanh(float v) {
    return 1.f - 2.f / (1.f + __expf(2.f * v));
}

// W_comb[g][f] = sum_e W_ih[g][e] * W_emb[e][f];  b_comb[g] = W_ih[g]·b_emb + b_ih[g] + b_hh[g]
__global__ __launch_bounds__(256) void k_wcomb(const float* __restrict__ W_emb,
                                               const float* __restrict__ b_emb,
                                               const float* __restrict__ W_ih,
                                               const float* __restrict__ b_ih,
                                               const float* __restrict__ b_hh,
                                               float* __restrict__ W_comb,
                                               float* __restrict__ b_comb) {
    __shared__ float wih[4][NE];
    int g0 = blockIdx.x * 4;
    for (int i = threadIdx.x; i < 4 * NE; i += 256)
        wih[i >> 8][i & 255] = W_ih[(size_t)g0 * NE + i];
    __syncthreads();
    int gl = threadIdx.x >> 6, f = threadIdx.x & 63;
    float acc = 0.f;
    for (int e = 0; e < NE; ++e) acc += wih[gl][e] * W_emb[e * NF + f];
    W_comb[(size_t)(g0 + gl) * NF + f] = acc;
    if (f == 0) {
        float a2 = 0.f;
        for (int e = 0; e < NE; ++e) a2 += wih[gl][e] * b_emb[e];
        b_comb[g0 + gl] = a2 + b_ih[g0 + gl] + b_hh[g0 + gl];
    }
}

// Persistent LSTM recurrence, dense-A MFMA edition.
// 256 WGs = 4 batch-groups (16 rows, DENSE A) x 64 gate-slices (4 types x 8 h).
// Per WG/step: [16 x 576] @ [576 x 32] via mfma_f32_16x16x32_bf16 split-precision;
// waves = 2 n-tiles x 4 k-chunks (kt {5,5,4,4}); k-partials reduced in LDS.
// Exchange: producer-packed split-bf16 u32 words (agent stores) + per-producer
// t-indexed flags; consumer wave0 polls 64 flags (ballot), one agent acquire
// fence per step, then PLAIN u64 loads (L2-shared across same-XCD consumers).
__global__ __launch_bounds__(512, 2) void k_lstm(const float* __restrict__ x,
                                                 const float* __restrict__ W_hh,
                                                 const float* __restrict__ W_comb,
                                                 const float* __restrict__ b_comb,
                                                 unsigned int* __restrict__ bufHI,
                                                 unsigned int* __restrict__ bufLO,
                                                 float* __restrict__ pooled,
                                                 int* __restrict__ flags) {
    const int wg = blockIdx.x;
    const int grp = wg >> 6;           // 0..3
    const int slc = wg & 63;           // 0..63 -> h-idx [8*slc, 8*slc+8)
    const int tid = threadIdx.x;
    const int lane = tid & 63, wave = tid >> 6;
    const int m4 = lane & 15;          // A row (batch) / B col (gate)
    const int qq = lane >> 4;          // quad
    const int nt = wave >> 2;          // n-tile 0..1
    const int kq = wave & 3;           // k-chunk 0..3
    const int kt0 = (kq < 2) ? kq * 5 : 10 + (kq - 2) * 4;
    const int ktn = (kq < 2) ? 5 : 4;

    __shared__ __align__(16) unsigned short hAhi[RPG * SA];
    __shared__ __align__(16) unsigned short hAlo[RPG * SA];
    __shared__ __align__(16) float part[4 * 32 * 16];   // [kq][n_loc][b]
    __shared__ float gact[512];                          // [n_loc][b]
    __shared__ float bcl[32];

    // ---- B-fragments (register-resident, split bf16): 32 gate-rows of WG ----
    // n_loc = nt*16 + m4 -> type = n_loc>>3, j = n_loc&7, global row type*512+slc*8+j
    const int n_loc = nt * 16 + m4;
    const int grow = (n_loc >> 3) * NH + slc * 8 + (n_loc & 7);
    F8 bhi[5], blo[5];
    #pragma unroll
    for (int k = 0; k < 5; ++k) {
        if (k < ktn) {
            const int kt = kt0 + k;
            const float* wp = (kt < 16)
                ? W_hh  + (size_t)grow * NH + kt * 32 + qq * 8
                : W_comb + (size_t)grow * NF + (kt - 16) * 32 + qq * 8;
            const float4 w0 = *(const float4*)wp;
            const float4 w1 = *(const float4*)(wp + 4);
            float wf[8] = {w0.x, w0.y, w0.z, w0.w, w1.x, w1.y, w1.z, w1.w};
            #pragma unroll
            for (int e = 0; e < 8; ++e) {
                unsigned short hb = f2bf(wf[e]);
                bhi[k].u[e] = hb;
                blo[k].u[e] = f2bf(wf[e] - bf2f(hb));
            }
        }
    }

    if (tid < 32) bcl[tid] = b_comb[(tid >> 3) * NH + slc * 8 + (tid & 7)];

    // zero h-section of A (t=0 state)
    for (int i = tid; i < RPG * NH; i += 512) {
        int r = i >> 9, c = i & 511;
        hAhi[r * SA + c] = 0;
        hAlo[r * SA + c] = 0;
    }
    // stage x(0) into cols 512..575 (256 threads: r=tid>>4, qx=tid&15)
    float4 xpre = make_float4(0.f, 0.f, 0.f, 0.f);
    if (tid < 256) {
        const int r = tid >> 4, qx = tid & 15;
        const float4 xv = *(const float4*)&x[((size_t)(grp * RPG + r) * TS + 0) * NF + qx * 4];
        float xf[4] = {xv.x, xv.y, xv.z, xv.w};
        F4 phi, plo;
        #pragma unroll
        for (int e = 0; e < 4; ++e) {
            unsigned short hb = f2bf(xf[e]);
            phi.u[e] = hb;
            plo.u[e] = f2bf(xf[e] - bf2f(hb));
        }
        *(bf16x4*)&hAhi[r * SA + NH + qx * 4] = phi.s;
        *(bf16x4*)&hAlo[r * SA + NH + qx * 4] = plo.s;
    }

    float c_reg = 0.f, hsum = 0.f;  // live on tid<128
    __syncthreads();

    for (int t = 0; t < TS; ++t) {
        if (t > 0) {
            // wave 0 polls all 64 producer flag-pairs for step t-1
            if (wave == 0) {
                const u64* fp = (const u64*)(flags + ((size_t)(grp * TS + (t - 1)) * NSLC) * 2);
                int guard = 0;
                for (;;) {
                    u64 v = __hip_atomic_load(fp + lane, __ATOMIC_RELAXED,
                                              __HIP_MEMORY_SCOPE_AGENT);
                    if (__ballot(v == FLAGVAL) == ~0ull) break;
                    __builtin_amdgcn_s_sleep(1);
                    if (++guard > (1 << 22)) break;  // anti-hang escape
                }
                __builtin_amdgcn_fence(__ATOMIC_ACQUIRE, "agent");  // one L1/L2 inv per step
            }
            __syncthreads();  // #0: caches invalidated, flags confirmed

            // stage h(t-1): plain u64 loads (L2-shared) -> LDS, zero unpack
            {
                const int r = tid >> 5, c = tid & 31;
                const int rowbase = (((t - 1) & 1) * NB + grp * RPG + r) * 256;
                const u64* srcHI = (const u64*)(bufHI + rowbase);
                const u64* srcLO = (const u64*)(bufLO + rowbase);
                #pragma unroll
                for (int i = 0; i < 4; ++i) {
                    u64 ph = srcHI[c + 32 * i];
                    u64 pl = srcLO[c + 32 * i];
                    *(u64*)&hAhi[r * SA + 4 * c + 128 * i] = ph;
                    *(u64*)&hAlo[r * SA + 4 * c + 128 * i] = pl;
                }
            }
            // stage x(t) from prefetch regs
            if (tid < 256) {
                const int r = tid >> 4, qx = tid & 15;
                float xf[4] = {xpre.x, xpre.y, xpre.z, xpre.w};
                F4 phi, plo;
                #pragma unroll
                for (int e = 0; e < 4; ++e) {
                    unsigned short hb = f2bf(xf[e]);
                    phi.u[e] = hb;
                    plo.u[e] = f2bf(xf[e] - bf2f(hb));
                }
                *(bf16x4*)&hAhi[r * SA + NH + qx * 4] = phi.s;
                *(bf16x4*)&hAlo[r * SA + NH + qx * 4] = plo.s;
            }
        }
        // prefetch x(t+1)
        if (t + 1 < TS && tid < 256) {
            const int r = tid >> 4, qx = tid & 15;
            xpre = *(const float4*)&x[((size_t)(grp * RPG + r) * TS + (t + 1)) * NF + qx * 4];
        }
        __syncthreads();  // #1: A ready

        // ---- MFMA: dense [16 x k-chunk] @ [k-chunk x 16], 3 split chains ----
        f32x4 acc0 = {0.f, 0.f, 0.f, 0.f};
        f32x4 acc1 = {0.f, 0.f, 0.f, 0.f};
        f32x4 acc2 = {0.f, 0.f, 0.f, 0.f};
        {
            const int abase = m4 * SA;
            #pragma unroll
            for (int k = 0; k < 5; ++k) {
                if (k < ktn) {
                    const int kt = kt0 + k;
                    const bf16x8 ah = *(const bf16x8*)&hAhi[abase + kt * 32 + qq * 8];
                    const bf16x8 al = *(const bf16x8*)&hAlo[abase + kt * 32 + qq * 8];
                    acc0 = __builtin_amdgcn_mfma_f32_16x16x32_bf16(ah, bhi[k].s, acc0, 0, 0, 0);
                    acc1 = __builtin_amdgcn_mfma_f32_16x16x32_bf16(al, bhi[k].s, acc1, 0, 0, 0);
                    acc2 = __builtin_amdgcn_mfma_f32_16x16x32_bf16(ah, blo[k].s, acc2, 0, 0, 0);
                }
            }
        }
        {
            const f32x4 a = acc0 + acc1 + acc2;
            // D[m=qq*4+e][n=m4]: part[kq][n_loc][b=qq*4+e]
            *(float4*)&part[kq * 512 + n_loc * 16 + qq * 4] = make_float4(a.x, a.y, a.z, a.w);
        }
        __syncthreads();  // #2: partials ready

        // k-reduce + bias + activation; thread = (g2 = tid>>4, b = tid&15)
        {
            const int g2 = tid >> 4;
            const float v = part[tid] + part[512 + tid] + part[1024 + tid] +
                            part[1536 + tid] + bcl[g2];
            float a;
            if ((g2 >> 3) == 2) a = fast_tanh(v);      // cell gate
            else                a = fast_sigmoid(v);   // i,f,o
            gact[tid] = a;
        }
        __syncthreads();  // #3: gact ready

        // c/h update on tid<128: (j = tid>>4 in 0..7, b = tid&15)
        if (tid < 128) {
            const int j = tid >> 4, b = tid & 15;
            const float iv = gact[tid], fv = gact[128 + tid];
            const float gv = gact[256 + tid], ov = gact[384 + tid];
            c_reg = fv * c_reg + iv * gv;
            const float h = ov * fast_tanh(c_reg);
            hsum += h;
            // producer-side split-bf16 packing: pair (j, j^1) -> one HI word + one LO word
            const unsigned short hb = f2bf(h);
            const unsigned short lb = f2bf(h - bf2f(hb));
            const unsigned int pk = ((unsigned)hb << 16) | lb;
            const unsigned int pp = (unsigned)__shfl_xor((int)pk, 16);
            if ((j & 1) == 0) {
                const int widx = ((t & 1) * NB + grp * RPG + b) * 256 + slc * 4 + (j >> 1);
                __hip_atomic_store(&bufHI[widx], (pp & 0xffff0000u) | (pk >> 16),
                                   __ATOMIC_RELAXED, __HIP_MEMORY_SCOPE_AGENT);
                __hip_atomic_store(&bufLO[widx], (pp << 16) | (pk & 0xffffu),
                                   __ATOMIC_RELAXED, __HIP_MEMORY_SCOPE_AGENT);
            }
            // publish: each writer wave waits its own stores' ack, sets its flag word
            if ((tid & 63) == 0) {
                __asm__ volatile("" ::: "memory");      // no compiler reordering
                __builtin_amdgcn_s_waitcnt(0x0f70);     // vmcnt(0)
                __hip_atomic_store(&flags[((size_t)(grp * TS + t) * NSLC + slc) * 2 + (tid >> 6)],
                                   1, __ATOMIC_RELAXED, __HIP_MEMORY_SCOPE_AGENT);
            }
        }
        // no trailing barrier: next step's poll + barrier #0/#1 cover hazards
    }

    if (tid < 128) {
        const int j = tid >> 4, b = tid & 15;
        pooled[(size_t)(grp * RPG + b) * NH + slc * 8 + j] = hsum * (1.f / TS);
    }
}

// out[b][o] = pooled[b]·W_fc[o] + b_fc[o]
__global__ __launch_bounds__(256) void k_fc(const float* __restrict__ pooled,
                                            const float* __restrict__ W_fc,
                                            const float* __restrict__ b_fc,
                                            float* __restrict__ out) {
    __shared__ float pl[2][NH];
    const int b0 = blockIdx.x * 2;
    for (int i = threadIdx.x; i < 2 * NH; i += 256)
        pl[i >> 9][i & 511] = pooled[(size_t)b0 * NH + i];
    __syncthreads();
    const int o = threadIdx.x & 127, bl = threadIdx.x >> 7;
    const float* wr = W_fc + (size_t)o * NH;
    float acc = 0.f;
    #pragma unroll 4
    for (int k = 0; k < NH; k += 4) {
        const float4 wv = *(const float4*)&wr[k];
        acc += pl[bl][k] * wv.x + pl[bl][k + 1] * wv.y +
               pl[bl][k + 2] * wv.z + pl[bl][k + 3] * wv.w;
    }
    out[(size_t)(b0 + bl) * NO + o] = acc + b_fc[o];
}

extern "C" void kernel_launch(void* const* d_in, const int* in_sizes, int n_in,
                              void* d_out, int out_size, void* d_ws, size_t ws_size,
                              hipStream_t stream) {
    const float* x     = (const float*)d_in[0];
    const float* W_emb = (const float*)d_in[1];
    const float* b_emb = (const float*)d_in[2];
    const float* W_ih  = (const float*)d_in[3];
    const float* W_hh  = (const float*)d_in[4];
    const float* b_ih  = (const float*)d_in[5];
    const float* b_hh  = (const float*)d_in[6];
    const float* W_fc  = (const float*)d_in[7];
    const float* b_fc  = (const float*)d_in[8];
    float* out = (float*)d_out;
    float* ws  = (float*)d_ws;

    float* W_comb = ws + OFF_WCOMB;
    float* b_comb = ws + OFF_BCOMB;
    unsigned int* bufHI = (unsigned int*)(ws + OFF_BUFHI);
    unsigned int* bufLO = (unsigned int*)(ws + OFF_BUFLO);
    float* pooled = ws + OFF_POOL;
    int*   flags  = (int*)(ws + OFF_FLAGS);

    hipLaunchKernelGGL(k_wcomb, dim3(512), dim3(256), 0, stream,
                       W_emb, b_emb, W_ih, b_ih, b_hh, W_comb, b_comb);
    hipLaunchKernelGGL(k_lstm,  dim3(256), dim3(512), 0, stream,
                       x, W_hh, W_comb, b_comb, bufHI, bufLO, pooled, flags);
    hipLaunchKernelGGL(k_fc,    dim3(32),  dim3(256), 0, stream,
                       pooled, W_fc, b_fc, out);
}